// Round 8
// baseline (306.027 us; speedup 1.0000x reference)
//
#include <hip/hip_runtime.h>

// PhaseCoherenceLoss — R8: DISCRIMINATION PROBE. pcl_main launched TWICE
// (idempotent). main_warm = dur_us - 271.4 tells us whether the ~74us
// cold-pass cost is memory-source-bound (warm ~30-45us -> roofline) or
// kernel-structure-bound (warm ~74us -> keep hunting).
//
// R1: same-address atomics serialized (392us @3%BW) -> two-stage reduction.
// R3/R5/R6/R7: four load structures (48B-stride float4, shfl-overlap,
//   scattered dwordx3, slab-contiguous dwordx3) all ~272us total -> pcl_main
//   ~74us invariant. Not coalescing, not locality, not ILP.

#define NTHREADS  256
#define SLAB      2048          // timesteps per block (24 KB)
#define JITER     8             // SLAB / NTHREADS
#define TLEN      8192          // timesteps per row; 4 slabs per row

struct alignas(4) F3 { float a, b, c; };

__device__ __forceinline__ F3 load_f3(const float* __restrict__ p) {
    F3 v;
    __builtin_memcpy(&v, p, sizeof(F3));   // 12B -> global_load_dwordx3
    return v;
}

// pack (bits(max) & ~3) | argidx — strict > keeps first-max tie-break.
// 2 low mantissa bits dropped: 2^-21 rel err on loss, vs 0.255 abs threshold.
__device__ __forceinline__ int argmax3_pack(F3 v) {
    float bm = v.a; int bi = 0;
    if (v.b > bm) { bm = v.b; bi = 1; }
    if (v.c > bm) { bm = v.c; bi = 2; }
    return (__float_as_int(bm) & ~3) | bi;
}

__global__ __launch_bounds__(NTHREADS) void pcl_main(const float* __restrict__ x,
                                                     float* __restrict__ part_loss,
                                                     unsigned int* __restrict__ part_cnt) {
    const int tid  = threadIdx.x;
    const int lane = tid & 63;
    const int wv   = tid >> 6;
    const float* xb = x + (size_t)blockIdx.x * SLAB * 3;

    // contiguous slab: thread reads timestep (tid + j*256); wave = 768B contig
    F3 own[JITER];
    #pragma unroll
    for (int j = 0; j < JITER; ++j)
        own[j] = load_f3(xb + (size_t)3 * (tid + j * NTHREADS));

    // cross-slab successor (timestep slab_base+2048), unless row end
    const bool has_next = ((blockIdx.x & 3u) != 3u);    // TLEN/SLAB = 4 slabs/row
    F3 nextv = own[0];
    if (tid == NTHREADS - 1 && has_next)
        nextv = load_f3(xb + (size_t)3 * SLAB);

    int pk[JITER];
    #pragma unroll
    for (int j = 0; j < JITER; ++j) pk[j] = argmax3_pack(own[j]);

    // wave-boundary successor table: lane-0 packs of each wave
    __shared__ int sm[4][JITER];
    if (lane == 0) {
        #pragma unroll
        for (int j = 0; j < JITER; ++j) sm[wv][j] = pk[j];
    }
    __syncthreads();

    float loss = 0.0f;
    unsigned int cnt = 0;
    #pragma unroll
    for (int j = 0; j < JITER; ++j) {
        int npk = __shfl_down(pk[j], 1, 64);            // successor = tid+1, same j
        if (lane == 63) {
            if (wv < 3)              npk = sm[wv + 1][j];        // next wave, same j
            else if (j < JITER - 1)  npk = sm[0][j + 1];         // tid 255 -> tid 0, j+1
            else                     npk = argmax3_pack(nextv);  // cross-slab
        }
        bool valid = !(wv == 3 && lane == 63 && j == JITER - 1 && !has_next);
        if (valid) {
            int code = (pk[j] & 3) * 3 + (npk & 3);
            if ((0xCC >> code) & 1) {
                float nmx = __int_as_float(npk & ~3);
                loss = fmaf(nmx, nmx, loss);
                cnt++;
            }
        }
    }

    // wave-64 reduce
    #pragma unroll
    for (int off = 32; off > 0; off >>= 1) {
        loss += __shfl_down(loss, off, 64);
        cnt  += __shfl_down(cnt,  off, 64);
    }

    __shared__ float        sl[4];
    __shared__ unsigned int sc[4];
    if (lane == 0) { sl[wv] = loss; sc[wv] = cnt; }
    __syncthreads();

    if (tid == 0) {
        part_loss[blockIdx.x] = sl[0] + sl[1] + sl[2] + sl[3];
        part_cnt[blockIdx.x]  = sc[0] + sc[1] + sc[2] + sc[3];
    }
}

__global__ __launch_bounds__(NTHREADS) void pcl_final(const float* __restrict__ part_loss,
                                                      const unsigned int* __restrict__ part_cnt,
                                                      float* __restrict__ out, int npart) {
    double L = 0.0;
    unsigned int C = 0;
    for (int i = threadIdx.x; i < npart; i += NTHREADS) {
        L += (double)part_loss[i];
        C += part_cnt[i];
    }
    #pragma unroll
    for (int off = 32; off > 0; off >>= 1) {
        L += __shfl_down(L, off, 64);
        C += __shfl_down(C, off, 64);
    }
    __shared__ double       sl[4];
    __shared__ unsigned int sc[4];
    int lane = threadIdx.x & 63;
    int wid  = threadIdx.x >> 6;
    if (lane == 0) { sl[wid] = L; sc[wid] = C; }
    __syncthreads();
    if (threadIdx.x == 0) {
        double       Lt = sl[0] + sl[1] + sl[2] + sl[3];
        unsigned int Ct = sc[0] + sc[1] + sc[2] + sc[3];
        out[0] = (Ct > 0u) ? (float)(10.0 * Lt / (double)Ct) : 0.0f;
    }
}

extern "C" void kernel_launch(void* const* d_in, const int* in_sizes, int n_in,
                              void* d_out, int out_size, void* d_ws, size_t ws_size,
                              hipStream_t stream) {
    const float* x = (const float*)d_in[0];
    const int B = in_sizes[0] / (3 * TLEN);
    const int grid = B * (TLEN / SLAB);                 // 8192 for B=2048

    float*        part_loss = (float*)d_ws;
    unsigned int* part_cnt  = (unsigned int*)((char*)d_ws + (size_t)grid * sizeof(float));

    // PROBE: launch twice. Second pass reads L3-warm data and overwrites the
    // partials with identical values (idempotent -> output unchanged).
    // main_warm = dur_us - 271.4 discriminates memory-floor vs kernel-defect.
    pcl_main<<<grid, NTHREADS, 0, stream>>>(x, part_loss, part_cnt);
    pcl_main<<<grid, NTHREADS, 0, stream>>>(x, part_loss, part_cnt);
    pcl_final<<<1, NTHREADS, 0, stream>>>(part_loss, part_cnt, (float*)d_out, grid);
}

// Round 9
// 259.099 us; speedup vs baseline: 1.1811x; 1.1811x over previous
//
#include <hip/hip_runtime.h>

// PhaseCoherenceLoss: scalar reduction over (B, T=8192, 3) fp32 logits.
// pair (t,t+1): pt=argmax[t], pt1=argmax[t+1]; illegal[pt][pt1] ->
// loss += (max logit at t+1)^2, cnt++. out = cnt>0 ? 10*loss/cnt : 0.
// Illegal codes pt*3+pt1 in {2,3,6,7} -> bitmask 0xCC.
//
// History: R1 atomics serialized (392us). R3-R7: four load structures all
//   ~74us cold. R8 probe: WARM pass = 31us (6.5 TB/s = ceiling) -> kernel
//   exonerated; cold cost is harness L3 state (805MB poison leaves ~half of
//   d_in L3-resident, scattered per-line -> miss pattern defeats DRAM
//   locality, ~2.7 TB/s blended).
// R9: NON-TEMPORAL loads (global_load_dwordx4 nt) stream all of d_in from
//   HBM in one monotonic sweep, no L3 allocation/eviction churn. Slab staged
//   through LDS so nt loads are perfect lane-linear float4; compute reads
//   timestep+successor from LDS (no shfl, no boundary tables).

#define NTHREADS  256
#define SLAB      2048            // timesteps per block
#define JITER     8               // SLAB / NTHREADS
#define F4_PER_BLK 1536           // SLAB*3/4 float4 per slab
#define TLEN      8192            // timesteps per row; 4 slabs per row

typedef float f4v __attribute__((ext_vector_type(4)));

struct F3 { float a, b, c; };

// pack (bits(max) & ~3) | argidx — strict > keeps first-max tie-break.
// 2 low mantissa bits dropped: 2^-21 rel err, vs 0.255 abs threshold.
__device__ __forceinline__ int argmax3_pack(F3 v) {
    float bm = v.a; int bi = 0;
    if (v.b > bm) { bm = v.b; bi = 1; }
    if (v.c > bm) { bm = v.c; bi = 2; }
    return (__float_as_int(bm) & ~3) | bi;
}

__global__ __launch_bounds__(NTHREADS) void pcl_main(const float* __restrict__ x,
                                                     float* __restrict__ part_loss,
                                                     unsigned int* __restrict__ part_cnt) {
    const int tid = threadIdx.x;
    __shared__ float sx[SLAB * 3 + 4];                 // slab + cross-slab pad

    // ---- stage slab via non-temporal lane-linear float4 ----
    const f4v* xb4 = (const f4v*)x + (size_t)blockIdx.x * F4_PER_BLK;
    f4v* sx4 = (f4v*)sx;
    #pragma unroll
    for (int j = 0; j < F4_PER_BLK / NTHREADS; ++j) {
        int i = j * NTHREADS + tid;
        sx4[i] = __builtin_nontemporal_load(xb4 + i);
    }
    const bool has_next = ((blockIdx.x & 3u) != 3u);   // 4 slabs per row
    if (tid == 0 && has_next)
        sx4[F4_PER_BLK] = __builtin_nontemporal_load(xb4 + F4_PER_BLK);
    __syncthreads();

    // ---- compute: thread handles timesteps tid + j*256; successor from LDS ----
    float loss = 0.0f;
    unsigned int cnt = 0;
    #pragma unroll
    for (int j = 0; j < JITER; ++j) {
        int t = tid + j * NTHREADS;
        F3 cur = *(const F3*)(sx + 3 * t);
        F3 nxt = *(const F3*)(sx + 3 * t + 3);         // pad covers t=2047 (garbage if !has_next, discarded)
        bool valid = !(t == SLAB - 1 && !has_next);    // skip row-last timestep
        if (valid) {
            int pc = argmax3_pack(cur);
            int pn = argmax3_pack(nxt);
            int code = (pc & 3) * 3 + (pn & 3);
            if ((0xCC >> code) & 1) {
                float nmx = __int_as_float(pn & ~3);
                loss = fmaf(nmx, nmx, loss);
                cnt++;
            }
        }
    }

    // ---- wave + block reduce ----
    #pragma unroll
    for (int off = 32; off > 0; off >>= 1) {
        loss += __shfl_down(loss, off, 64);
        cnt  += __shfl_down(cnt,  off, 64);
    }
    __shared__ float        sl[4];
    __shared__ unsigned int sc[4];
    int lane = tid & 63, wv = tid >> 6;
    if (lane == 0) { sl[wv] = loss; sc[wv] = cnt; }
    __syncthreads();
    if (tid == 0) {
        part_loss[blockIdx.x] = sl[0] + sl[1] + sl[2] + sl[3];
        part_cnt[blockIdx.x]  = sc[0] + sc[1] + sc[2] + sc[3];
    }
}

__global__ __launch_bounds__(NTHREADS) void pcl_final(const float* __restrict__ part_loss,
                                                      const unsigned int* __restrict__ part_cnt,
                                                      float* __restrict__ out, int npart) {
    double L = 0.0;
    unsigned int C = 0;
    for (int i = threadIdx.x; i < npart; i += NTHREADS) {
        L += (double)part_loss[i];
        C += part_cnt[i];
    }
    #pragma unroll
    for (int off = 32; off > 0; off >>= 1) {
        L += __shfl_down(L, off, 64);
        C += __shfl_down(C, off, 64);
    }
    __shared__ double       sl[4];
    __shared__ unsigned int sc[4];
    int lane = threadIdx.x & 63, wid = threadIdx.x >> 6;
    if (lane == 0) { sl[wid] = L; sc[wid] = C; }
    __syncthreads();
    if (threadIdx.x == 0) {
        double       Lt = sl[0] + sl[1] + sl[2] + sl[3];
        unsigned int Ct = sc[0] + sc[1] + sc[2] + sc[3];
        out[0] = (Ct > 0u) ? (float)(10.0 * Lt / (double)Ct) : 0.0f;
    }
}

extern "C" void kernel_launch(void* const* d_in, const int* in_sizes, int n_in,
                              void* d_out, int out_size, void* d_ws, size_t ws_size,
                              hipStream_t stream) {
    const float* x = (const float*)d_in[0];
    const int B = in_sizes[0] / (3 * TLEN);
    const int grid = B * (TLEN / SLAB);                // 8192 for B=2048

    float*        part_loss = (float*)d_ws;
    unsigned int* part_cnt  = (unsigned int*)((char*)d_ws + (size_t)grid * sizeof(float));

    // All partial slots written unconditionally each call -> no memset needed
    // despite the 0xAA ws re-poison.
    pcl_main<<<grid, NTHREADS, 0, stream>>>(x, part_loss, part_cnt);
    pcl_final<<<1, NTHREADS, 0, stream>>>(part_loss, part_cnt, (float*)d_out, grid);
}